// Round 3
// baseline (439.579 us; speedup 1.0000x reference)
//
#include <hip/hip_runtime.h>
#include <math.h>

#define NN 1024
#define FD 64
#define CH 32          // K*H
#define M1D 9
#define M2D 505
#define QH 253         // q in [0,252] stored
#define THALF 2273     // half-grid points
#define KPAD 4608
#define KSPLIT 8
#define KCHUNK 576     // 4608/8 = 18*32
#define NCHUNK 512     // nodes per A2 chunk (4 chunks)

// ws layout (floats)
#define OFF_TW    0                       // 1010 (pad 1024)
#define OFF_WP    1024                    // 18 (pad 32)
#define OFF_SUMX  1056                    // 128 (pad to 1184)
#define OFF_G1    1184                    // 9*253*64*2 = 291456
#define OFF_GMAT  292640                  // 4608*64 = 294912
#define OFF_XL    587552                  // 65536
#define OFF_XR    653088                  // 65536
#define OFF_AGG   718624                  // 2048*512 = 1048576 ; ALIASED as partials (8*131072) later
#define OFF_Y     1767200                 // 2048*4608 = 9437184 ; first 259072 ALIASED as T early
#define OFF_A2    11204384                // 4096*512 = 2097152 (one chunk)
#define OFF_WT    13301536                // 64*512 = 32768
// total = 13,334,304 floats = 53.3 MB

__global__ __launch_bounds__(512) void prep_kernel(float* __restrict__ tw,
                                                   float* __restrict__ wp,
                                                   float* __restrict__ sumx) {
    int t = threadIdx.x;
    if (t < M2D) {
        double a = -2.0 * M_PI * (double)t / (double)M2D;
        tw[2*t] = (float)cos(a); tw[2*t+1] = (float)sin(a);
    }
    if (t < M1D) {
        double a = -2.0 * M_PI * (double)t / (double)M1D;
        wp[2*t] = (float)cos(a); wp[2*t+1] = (float)sin(a);
    }
    if (t < 128) sumx[t] = 0.f;
}

// T[r][m2] (row stride 512): r=2q+reim. T[2q][m2]=cos(-2pi q m2/505), T[2q+1][m2]=-sin(-..)
__global__ __launch_bounds__(256) void buildT_kernel(const float* __restrict__ tw,
                                                     float* __restrict__ T) {
    int idx = blockIdx.x * 256 + threadIdx.x;
    if (idx >= 506 * 512) return;
    int r = idx >> 9, m2 = idx & 511;
    float v = 0.f;
    if (m2 < M2D) {
        int q = r >> 1;
        int t = (q * m2) % M2D;
        v = (r & 1) ? -tw[2*t+1] : tw[2*t];
    }
    T[idx] = v;
}

// Wt[m][col] (row stride 512): col=2q+reim. Wt[m][2q]=cos(-2pi q m/505), [2q+1]=sin(-..)
__global__ __launch_bounds__(256) void buildWt_kernel(const float* __restrict__ tw,
                                                      float* __restrict__ Wt) {
    int idx = blockIdx.x * 256 + threadIdx.x;
    if (idx >= 64 * 512) return;
    int m = idx >> 9, col = idx & 511;
    float v = 0.f;
    if (col < 506) {
        int q = col >> 1;
        int t = (q * m) % M2D;
        v = (col & 1) ? tw[2*t+1] : tw[2*t];
    }
    Wt[idx] = v;
}

// 32 blocks x 64 threads: partial column sums of x
__global__ __launch_bounds__(64) void sumx_kernel(const float* __restrict__ x,
                                                  float* __restrict__ sumx) {
    int b = blockIdx.x >> 4, chunk = blockIdx.x & 15;
    int f = threadIdx.x;
    const float* xb = x + (size_t)b * NN * FD;
    float acc = 0.f;
    int j0 = chunk * 64;
    #pragma unroll 4
    for (int j = j0; j < j0 + 64; j++) acc += xb[j*FD + f];
    atomicAdd(&sumx[b*FD + f], acc);
}

// 2048 blocks x 64 threads: xl = x@Wl+bl, xr = x@Wr+br
__global__ __launch_bounds__(64) void proj_kernel(const float* __restrict__ x,
                                                  const float* __restrict__ Wl, const float* __restrict__ bl,
                                                  const float* __restrict__ Wr, const float* __restrict__ br,
                                                  float* __restrict__ xl, float* __restrict__ xr) {
    int node = blockIdx.x, tid = threadIdx.x;
    __shared__ float xrow[FD];
    xrow[tid] = x[(size_t)node*FD + tid];
    __syncthreads();
    int c = tid & 31;
    const float* W = (tid < 32) ? Wl : Wr;
    float acc = (tid < 32) ? bl[c] : br[c];
    #pragma unroll
    for (int f = 0; f < FD; f++) acc += xrow[f] * W[f*CH + c];
    float* dst = (tid < 32) ? xl : xr;
    dst[(size_t)node*CH + c] = acc;
}

// G1 rows = T @ Wm[m1] : per m1, [506 x 505(pad512)] @ [505 x 64]
__global__ __launch_bounds__(256) void g1_gemm_kernel(const float* __restrict__ T,
                                                      const float* __restrict__ Wm,
                                                      float* __restrict__ G1) {
    int mt = blockIdx.x, m1 = blockIdx.y;
    int tid = threadIdx.x;
    __shared__ float Ts[64][33];
    __shared__ float Ws[32][64];
    const float* Wmb = Wm + (size_t)m1 * M2D * FD;
    float acc[4][4] = {{0.f}};
    int tm = (tid >> 4) * 4, tf = (tid & 15) * 4;
    int r0 = mt * 64;
    for (int k0 = 0; k0 < 512; k0 += 32) {
        for (int l = tid; l < 2048; l += 256) {
            int r = l >> 5, kk = l & 31;
            int rr = r0 + r;
            Ts[r][kk] = (rr < 506) ? T[(size_t)rr*512 + k0 + kk] : 0.f;
        }
        for (int l = tid; l < 2048; l += 256) {
            int kk = l >> 6, f = l & 63;
            int krow = k0 + kk;
            Ws[kk][f] = (krow < M2D) ? Wmb[(size_t)krow*FD + f] : 0.f;
        }
        __syncthreads();
        #pragma unroll 8
        for (int k = 0; k < 32; k++) {
            float a0 = Ts[tm][k], a1 = Ts[tm+1][k], a2 = Ts[tm+2][k], a3 = Ts[tm+3][k];
            float4 b = *(const float4*)&Ws[k][tf];
            acc[0][0] += a0*b.x; acc[0][1] += a0*b.y; acc[0][2] += a0*b.z; acc[0][3] += a0*b.w;
            acc[1][0] += a1*b.x; acc[1][1] += a1*b.y; acc[1][2] += a1*b.z; acc[1][3] += a1*b.w;
            acc[2][0] += a2*b.x; acc[2][1] += a2*b.y; acc[2][2] += a2*b.z; acc[2][3] += a2*b.w;
            acc[3][0] += a3*b.x; acc[3][1] += a3*b.y; acc[3][2] += a3*b.z; acc[3][3] += a3*b.w;
        }
        __syncthreads();
    }
    #pragma unroll
    for (int i = 0; i < 4; i++) {
        int r = r0 + tm + i;
        if (r >= 506) continue;
        int q = r >> 1, reim = r & 1;
        size_t base = (size_t)(m1*QH + q) * FD;
        #pragma unroll
        for (int j = 0; j < 4; j++)
            G1[(base + tf + j)*2 + reim] = acc[i][j];
    }
}

// Gmat[2t..2t+1][f] from G1: fold 9-point DFT over m1, Hermitian weight, 1/4545
__global__ __launch_bounds__(64) void gmat_kernel(const float* __restrict__ G1,
                                                  const float* __restrict__ wp,
                                                  float* __restrict__ Gmat) {
    int t = blockIdx.x;            // [0, 2304)
    int f = threadIdx.x;
    if (t >= THALF) {
        Gmat[(size_t)(2*t)*FD + f] = 0.f;
        Gmat[(size_t)(2*t+1)*FD + f] = 0.f;
        return;
    }
    int p, q;
    if (t < QH) { p = 0; q = t; }
    else { int u = t - QH; p = 1 + u / M2D; q = u % M2D; }
    float gr = 0.f, gi = 0.f;
    #pragma unroll
    for (int m1 = 0; m1 < M1D; m1++) {
        float ar, ai;
        if (q < QH) { size_t o = ((size_t)(m1*QH + q)*FD + f)*2; ar = G1[o]; ai = G1[o+1]; }
        else        { size_t o = ((size_t)(m1*QH + (M2D - q))*FD + f)*2; ar = G1[o]; ai = -G1[o+1]; }
        int pm = (p * m1) % M1D;
        float cr = wp[2*pm], ci = -wp[2*pm+1];   // cis(+2 pi p m1 / 9)
        gr += ar*cr - ai*ci;
        gi += ar*ci + ai*cr;
    }
    float cfac = (t == 0) ? 1.0f : 2.0f;
    float scale = cfac / 4545.0f;
    Gmat[(size_t)(2*t)*FD + f]   =  gr * scale;
    Gmat[(size_t)(2*t+1)*FD + f] = -gi * scale;
}

// one block (256 thr) per node: softmax Z over all j, sparse clamped gather
__global__ __launch_bounds__(256) void attn_agg_kernel(const float* __restrict__ x,
                                                       const float* __restrict__ adj,
                                                       const float* __restrict__ xl,
                                                       const float* __restrict__ xr,
                                                       const float* __restrict__ sumx,
                                                       float* __restrict__ agg) {
    int node = blockIdx.x;
    int b = node >> 10;
    int tid = threadIdx.x;
    __shared__ float xr_s[CH], Zinv[CH], Ssum[CH];
    __shared__ float red[8][CH];
    __shared__ int act_list[NN];
    __shared__ int act_n;
    __shared__ float qv[8][CH];

    if (tid < CH) xr_s[tid] = xr[(size_t)node*CH + tid];
    if (tid == 0) act_n = 0;
    __syncthreads();

    int c = tid & 31, jl = tid >> 5;
    const float* xlb = xl + ((size_t)b << 10) * CH;
    float zacc = 0.f;
    #pragma unroll 4
    for (int j = jl; j < NN; j += 8) {
        float s = xlb[j*CH + c] + xr_s[c];
        s = s > 0.f ? s : 0.01f * s;
        zacc += __expf(s);
    }
    red[jl][c] = zacc;
    __syncthreads();
    if (tid < CH) {
        float z = 0.f;
        #pragma unroll
        for (int r = 0; r < 8; r++) z += red[r][tid];
        Zinv[tid] = 1.0f / z;
    }
    const float* adjrow = adj + (size_t)node * NN;
    __syncthreads();
    for (int j = tid; j < NN; j += 256) {
        if (adjrow[j] != 0.f) { int p = atomicAdd(&act_n, 1); act_list[p] = j; }
    }
    __syncthreads();
    int nact = act_n;

    float acc0 = 0.f, acc1 = 0.f, sacc = 0.f;
    int f = tid & 63, n0 = tid >> 6;
    int g = f >> 4;
    int c0 = n0*4 + g, c1 = (n0+4)*4 + g;
    const float* xb = x + ((size_t)b << 10) * FD;

    for (int base = 0; base < nact; base += 8) {
        int cnt = min(8, nact - base);
        if (jl < cnt) {
            int j = act_list[base + jl];
            float s = xlb[j*CH + c] + xr_s[c];
            s = s > 0.f ? s : 0.01f * s;
            float p = __expf(s) * Zinv[c];
            float qq = fmaxf(p, 1e-6f) - 1e-6f;
            qv[jl][c] = qq;
            sacc += qq;
        }
        __syncthreads();
        for (int jb = 0; jb < cnt; jb++) {
            int j = act_list[base + jb];
            float xv = xb[j*FD + f];
            acc0 += qv[jb][c0] * xv;
            acc1 += qv[jb][c1] * xv;
        }
        __syncthreads();
    }
    red[jl][c] = sacc;
    __syncthreads();
    if (tid < CH) {
        float s = 0.f;
        #pragma unroll
        for (int r = 0; r < 8; r++) s += red[r][tid];
        Ssum[tid] = s + (float)NN * 1e-6f;
    }
    __syncthreads();
    float sx = sumx[b*FD + f] * 1e-6f;
    agg[(size_t)node*512 + n0*FD + f]       = (acc0 + sx) / Ssum[c0];
    agg[(size_t)node*512 + (n0+4)*FD + f]   = (acc1 + sx) / Ssum[c1];
}

// A2 = aggc @ Wt : [4096 x 64] @ [64 x 512] per chunk. grid (64 mtiles, 8 ntiles)
__global__ __launch_bounds__(256) void a_gemm_kernel(const float* __restrict__ aggc,
                                                     const float* __restrict__ Wt,
                                                     float* __restrict__ A2) {
    int mt = blockIdx.x, nt = blockIdx.y;
    int tid = threadIdx.x;
    __shared__ float As2[64][65];   // As2[k][r]
    __shared__ float Bs[64][64];    // Bs[k][c]
    float acc[4][4] = {{0.f}};
    int tm = (tid >> 4) * 4, tf = (tid & 15) * 4;
    for (int l = tid; l < 4096; l += 256) {
        int r = l >> 6, k = l & 63;
        As2[k][r] = aggc[(size_t)(mt*64 + r)*64 + k];
    }
    for (int l = tid; l < 4096; l += 256) {
        int k = l >> 6, cc = l & 63;
        Bs[k][cc] = Wt[(size_t)k*512 + nt*64 + cc];
    }
    __syncthreads();
    #pragma unroll 8
    for (int k = 0; k < 64; k++) {
        float a0 = As2[k][tm], a1 = As2[k][tm+1], a2 = As2[k][tm+2], a3 = As2[k][tm+3];
        float4 b = *(const float4*)&Bs[k][tf];
        acc[0][0] += a0*b.x; acc[0][1] += a0*b.y; acc[0][2] += a0*b.z; acc[0][3] += a0*b.w;
        acc[1][0] += a1*b.x; acc[1][1] += a1*b.y; acc[1][2] += a1*b.z; acc[1][3] += a1*b.w;
        acc[2][0] += a2*b.x; acc[2][1] += a2*b.y; acc[2][2] += a2*b.z; acc[2][3] += a2*b.w;
        acc[3][0] += a3*b.x; acc[3][1] += a3*b.y; acc[3][2] += a3*b.z; acc[3][3] += a3*b.w;
    }
    #pragma unroll
    for (int i = 0; i < 4; i++) {
        float4 v = make_float4(acc[i][0], acc[i][1], acc[i][2], acc[i][3]);
        *(float4*)&A2[(size_t)(mt*64 + tm + i)*512 + nt*64 + tf] = v;
    }
}

// one block (256 thr) per node: Y half-grid from A2 via complex products
__global__ __launch_bounds__(256) void y_kernel(const float* __restrict__ A2,
                                                const float* __restrict__ wp_g,
                                                float* __restrict__ Y, int node0) {
    int nl = blockIdx.x;
    int node = node0 + nl;
    int tid = threadIdx.x;
    __shared__ float2 AL[8][256];
    __shared__ float wpL[M1D*2];

    const float2* A2c = (const float2*)(A2 + (size_t)(nl*8)*512);
    for (int idx = tid; idx < 8*QH; idx += 256) {
        int n = idx / QH, q = idx % QH;
        AL[n][q] = A2c[n*256 + q];
    }
    if (tid < M1D*2) wpL[tid] = wp_g[tid];
    __syncthreads();

    float* Yrow = Y + (size_t)node * KPAD;
    for (int t = tid; t < KPAD/2; t += 256) {
        if (t >= THALF) { Yrow[2*t] = 0.f; Yrow[2*t+1] = 0.f; continue; }
        int p, q;
        if (t < QH) { p = 0; q = t; }
        else { int u = t - QH; p = 1 + u / M2D; q = u % M2D; }
        float cp = wpL[2*p], sp = wpL[2*p+1];      // e^{-2 pi i p / 9}
        int qq; float csign;
        if (q < QH) { qq = q; csign = 1.f; } else { qq = M2D - q; csign = -1.f; }
        float Pr = 1.f, Pi = 0.f, rp = 1.f;
        #pragma unroll
        for (int n = 0; n < 8; n++) {
            float2 Av = AL[n][qq];
            float Ar = Av.x, Ai = csign * Av.y;
            float Xr = cp - Ar, Xi = sp - Ai;
            float m2 = Xr*Xr + Xi*Xi;
            rp *= (sqrtf(m2) + 1e-6f);
            float nPr = Pr*Xr - Pi*Xi;
            Pi = Pr*Xi + Pi*Xr; Pr = nPr;
        }
        float pAbs = sqrtf(Pr*Pr + Pi*Pi);
        float rp8 = sqrtf(sqrtf(sqrtf(rp)));
        float s = rp8 / fmaxf(pAbs, 1e-20f);
        Yrow[2*t]   = s * Pr;
        Yrow[2*t+1] = s * Pi;
    }
}

// partials[kc] = Y[:, kc-chunk] @ Gmat[kc-chunk, :] ; grid (32 Mtiles, 8 kc)
__global__ __launch_bounds__(256) void gemm_kernel(const float* __restrict__ Y,
                                                   const float* __restrict__ Gmat,
                                                   float* __restrict__ part) {
    int mtile = blockIdx.x, kc = blockIdx.y;
    int tid = threadIdx.x;
    __shared__ float Yt2[32][65];   // Yt2[k][r] — [32][33] overflow was the round-2 bug
    __shared__ float Gt[32][64];
    int m0 = mtile * 64;
    int k0 = kc * KCHUNK;
    float acc[4][4] = {{0.f}};
    int tm = (tid >> 4) * 4;
    int tf = (tid & 15) * 4;
    for (int ks = 0; ks < KCHUNK; ks += 32) {
        for (int l = tid; l < 2048; l += 256) {
            int r = l >> 5, kk = l & 31;
            Yt2[kk][r] = Y[(size_t)(m0 + r)*KPAD + k0 + ks + kk];
        }
        for (int l = tid; l < 2048; l += 256) {
            int kk = l >> 6, cc = l & 63;
            Gt[kk][cc] = Gmat[(size_t)(k0 + ks + kk)*FD + cc];
        }
        __syncthreads();
        #pragma unroll 8
        for (int k = 0; k < 32; k++) {
            float a0 = Yt2[k][tm], a1 = Yt2[k][tm+1], a2 = Yt2[k][tm+2], a3 = Yt2[k][tm+3];
            float4 b = *(const float4*)&Gt[k][tf];
            acc[0][0] += a0*b.x; acc[0][1] += a0*b.y; acc[0][2] += a0*b.z; acc[0][3] += a0*b.w;
            acc[1][0] += a1*b.x; acc[1][1] += a1*b.y; acc[1][2] += a1*b.z; acc[1][3] += a1*b.w;
            acc[2][0] += a2*b.x; acc[2][1] += a2*b.y; acc[2][2] += a2*b.z; acc[2][3] += a2*b.w;
            acc[3][0] += a3*b.x; acc[3][1] += a3*b.y; acc[3][2] += a3*b.z; acc[3][3] += a3*b.w;
        }
        __syncthreads();
    }
    float* prow = part + (size_t)kc * (2048*FD);
    #pragma unroll
    for (int i = 0; i < 4; i++) {
        float4 v = make_float4(acc[i][0], acc[i][1], acc[i][2], acc[i][3]);
        *(float4*)&prow[(size_t)(m0 + tm + i)*FD + tf] = v;
    }
}

// sum 8 partials + bias + mask -> out
__global__ __launch_bounds__(256) void reduce_kernel(const float* __restrict__ part,
                                                     const float* __restrict__ bm,
                                                     const float* __restrict__ mask,
                                                     float* __restrict__ out) {
    int idx = blockIdx.x * 256 + threadIdx.x;   // float4 index over 2048*64/4 = 32768
    if (idx >= 32768) return;
    const float4* p4 = (const float4*)part;
    float4 s = p4[idx];
    #pragma unroll
    for (int kc = 1; kc < KSPLIT; kc++) {
        float4 v = p4[(size_t)kc*32768 + idx];
        s.x += v.x; s.y += v.y; s.z += v.z; s.w += v.w;
    }
    int f0 = (idx & 15) * 4;
    int node = idx >> 4;
    float mk = mask[node];
    s.x = (s.x + bm[f0])   * mk;
    s.y = (s.y + bm[f0+1]) * mk;
    s.z = (s.z + bm[f0+2]) * mk;
    s.w = (s.w + bm[f0+3]) * mk;
    ((float4*)out)[idx] = s;
}

extern "C" void kernel_launch(void* const* d_in, const int* in_sizes, int n_in,
                              void* d_out, int out_size, void* d_ws, size_t ws_size,
                              hipStream_t stream) {
    const float* x    = (const float*)d_in[0];
    const float* adj  = (const float*)d_in[1];
    const float* mask = (const float*)d_in[2];
    const float* Wl   = (const float*)d_in[3];
    const float* bl   = (const float*)d_in[4];
    const float* Wr   = (const float*)d_in[5];
    const float* br   = (const float*)d_in[6];
    const float* Wm   = (const float*)d_in[9];
    const float* bm   = (const float*)d_in[10];
    float* out = (float*)d_out;
    float* ws  = (float*)d_ws;

    float* tw   = ws + OFF_TW;
    float* wp   = ws + OFF_WP;
    float* sumx = ws + OFF_SUMX;
    float* G1   = ws + OFF_G1;
    float* Gmat = ws + OFF_GMAT;
    float* xl   = ws + OFF_XL;
    float* xr   = ws + OFF_XR;
    float* agg  = ws + OFF_AGG;
    float* part = ws + OFF_AGG;   // alias: agg dead before gemm_kernel
    float* T    = ws + OFF_Y;     // alias: T dead before y_kernel writes Y
    float* Y    = ws + OFF_Y;
    float* A2   = ws + OFF_A2;
    float* Wt   = ws + OFF_WT;

    hipLaunchKernelGGL(prep_kernel, dim3(1), dim3(512), 0, stream, tw, wp, sumx);
    hipLaunchKernelGGL(buildT_kernel, dim3((506*512+255)/256), dim3(256), 0, stream, tw, T);
    hipLaunchKernelGGL(buildWt_kernel, dim3(128), dim3(256), 0, stream, tw, Wt);
    hipLaunchKernelGGL(sumx_kernel, dim3(32), dim3(64), 0, stream, x, sumx);
    hipLaunchKernelGGL(proj_kernel, dim3(2048), dim3(64), 0, stream, x, Wl, bl, Wr, br, xl, xr);
    hipLaunchKernelGGL(g1_gemm_kernel, dim3(8, 9), dim3(256), 0, stream, T, Wm, G1);
    hipLaunchKernelGGL(gmat_kernel, dim3(KPAD/2), dim3(64), 0, stream, G1, wp, Gmat);
    hipLaunchKernelGGL(attn_agg_kernel, dim3(2048), dim3(256), 0, stream, x, adj, xl, xr, sumx, agg);
    for (int c = 0; c < 4; c++) {
        const float* aggc = agg + (size_t)c * NCHUNK * 512;
        hipLaunchKernelGGL(a_gemm_kernel, dim3(64, 8), dim3(256), 0, stream, aggc, Wt, A2);
        hipLaunchKernelGGL(y_kernel, dim3(NCHUNK), dim3(256), 0, stream, A2, wp, Y, c * NCHUNK);
    }
    hipLaunchKernelGGL(gemm_kernel, dim3(32, KSPLIT), dim3(256), 0, stream, Y, Gmat, part);
    hipLaunchKernelGGL(reduce_kernel, dim3(128), dim3(256), 0, stream, part, bm, mask, out);
}

// Round 4
// 308.117 us; speedup vs baseline: 1.4267x; 1.4267x over previous
//
#include <hip/hip_runtime.h>
#include <math.h>

#define NN 1024
#define FD 64
#define CH 32          // K*H
#define M1D 9
#define M2D 505
#define QH 253         // q in [0,252] stored
#define THALF 2273     // half-grid points
#define KPAD 4608
#define KSPLIT 8
#define KCHUNK 576     // 4608/8 = 18*32
#define NCHUNK 512     // nodes per A2 chunk (4 chunks)

// ws layout (floats)
#define OFF_TW    0                       // 1010 (pad 1024)
#define OFF_WP    1024                    // 18 (pad 32)
#define OFF_SUMX  1056                    // 128 (pad to 1184)
#define OFF_G1    1184                    // 9*253*64*2 = 291456
#define OFF_GMAT  292640                  // 4608*64 = 294912
#define OFF_XL    587552                  // 65536
#define OFF_XR    653088                  // 65536
#define OFF_AGG   718624                  // 2048*512 = 1048576 ; ALIASED as partials (8*131072) later
#define OFF_Y     1767200                 // 2048*4608 = 9437184 ; first 259072 ALIASED as T early
#define OFF_A2    11204384                // 4096*512 = 2097152 (one chunk)
#define OFF_WT    13301536                // 64*512 = 32768
// total = 13,334,304 floats = 53.3 MB

__global__ __launch_bounds__(512) void prep_kernel(float* __restrict__ tw,
                                                   float* __restrict__ wp,
                                                   float* __restrict__ sumx) {
    int t = threadIdx.x;
    if (t < M2D) {
        double a = -2.0 * M_PI * (double)t / (double)M2D;
        tw[2*t] = (float)cos(a); tw[2*t+1] = (float)sin(a);
    }
    if (t < M1D) {
        double a = -2.0 * M_PI * (double)t / (double)M1D;
        wp[2*t] = (float)cos(a); wp[2*t+1] = (float)sin(a);
    }
    if (t < 128) sumx[t] = 0.f;
}

// T[r][m2] (row stride 512): r=2q+reim. T[2q][m2]=cos(-2pi q m2/505), T[2q+1][m2]=-sin(-..)
__global__ __launch_bounds__(256) void buildT_kernel(const float* __restrict__ tw,
                                                     float* __restrict__ T) {
    int idx = blockIdx.x * 256 + threadIdx.x;
    if (idx >= 506 * 512) return;
    int r = idx >> 9, m2 = idx & 511;
    float v = 0.f;
    if (m2 < M2D) {
        int q = r >> 1;
        int t = (q * m2) % M2D;
        v = (r & 1) ? -tw[2*t+1] : tw[2*t];
    }
    T[idx] = v;
}

// Wt[m][col] (row stride 512): col=2q+reim. Wt[m][2q]=cos(-2pi q m/505), [2q+1]=sin(-..)
__global__ __launch_bounds__(256) void buildWt_kernel(const float* __restrict__ tw,
                                                      float* __restrict__ Wt) {
    int idx = blockIdx.x * 256 + threadIdx.x;
    if (idx >= 64 * 512) return;
    int m = idx >> 9, col = idx & 511;
    float v = 0.f;
    if (col < 506) {
        int q = col >> 1;
        int t = (q * m) % M2D;
        v = (col & 1) ? tw[2*t+1] : tw[2*t];
    }
    Wt[idx] = v;
}

// 32 blocks x 64 threads: partial column sums of x
__global__ __launch_bounds__(64) void sumx_kernel(const float* __restrict__ x,
                                                  float* __restrict__ sumx) {
    int b = blockIdx.x >> 4, chunk = blockIdx.x & 15;
    int f = threadIdx.x;
    const float* xb = x + (size_t)b * NN * FD;
    float acc = 0.f;
    int j0 = chunk * 64;
    #pragma unroll 4
    for (int j = j0; j < j0 + 64; j++) acc += xb[j*FD + f];
    atomicAdd(&sumx[b*FD + f], acc);
}

// 2048 blocks x 64 threads: xl = x@Wl+bl, xr = x@Wr+br
__global__ __launch_bounds__(64) void proj_kernel(const float* __restrict__ x,
                                                  const float* __restrict__ Wl, const float* __restrict__ bl,
                                                  const float* __restrict__ Wr, const float* __restrict__ br,
                                                  float* __restrict__ xl, float* __restrict__ xr) {
    int node = blockIdx.x, tid = threadIdx.x;
    __shared__ float xrow[FD];
    xrow[tid] = x[(size_t)node*FD + tid];
    __syncthreads();
    int c = tid & 31;
    const float* W = (tid < 32) ? Wl : Wr;
    float acc = (tid < 32) ? bl[c] : br[c];
    #pragma unroll
    for (int f = 0; f < FD; f++) acc += xrow[f] * W[f*CH + c];
    float* dst = (tid < 32) ? xl : xr;
    dst[(size_t)node*CH + c] = acc;
}

// G1 rows = T @ Wm[m1] : per m1, [506 x 505(pad512)] @ [505 x 64]
// Register-batched + double-buffered staging (round-3 fix: serial load->ds_write
// chains cost ~900 cyc/load; batching issues all 8 loads independently).
__global__ __launch_bounds__(256) void g1_gemm_kernel(const float* __restrict__ T,
                                                      const float* __restrict__ Wm,
                                                      float* __restrict__ G1) {
    int mt = blockIdx.x, m1 = blockIdx.y;
    int tid = threadIdx.x;
    __shared__ float Ts[64][33];
    __shared__ float Ws[32][64];
    const float* Wmb = Wm + (size_t)m1 * M2D * FD;
    float acc[4][4] = {{0.f}};
    int tm = (tid >> 4) * 4, tf = (tid & 15) * 4;
    int r0 = mt * 64;
    float ra[8], rb[8];
    // prologue: fetch tile k0=0 into registers
    #pragma unroll
    for (int i = 0; i < 8; i++) {
        int l = tid + i*256;
        int r = l >> 5, kk = l & 31;
        int rr = r0 + r;
        ra[i] = (rr < 506) ? T[(size_t)rr*512 + kk] : 0.f;
    }
    #pragma unroll
    for (int i = 0; i < 8; i++) {
        int l = tid + i*256;
        int kk = l >> 6, f = l & 63;
        rb[i] = (kk < M2D) ? Wmb[(size_t)kk*FD + f] : 0.f;
    }
    for (int k0 = 0; k0 < 512; k0 += 32) {
        #pragma unroll
        for (int i = 0; i < 8; i++) {
            int l = tid + i*256;
            Ts[l >> 5][l & 31] = ra[i];
        }
        #pragma unroll
        for (int i = 0; i < 8; i++) {
            int l = tid + i*256;
            Ws[l >> 6][l & 63] = rb[i];
        }
        __syncthreads();
        // prefetch next tile (flies during compute)
        if (k0 + 32 < 512) {
            int kn = k0 + 32;
            #pragma unroll
            for (int i = 0; i < 8; i++) {
                int l = tid + i*256;
                int r = l >> 5, kk = l & 31;
                int rr = r0 + r;
                ra[i] = (rr < 506) ? T[(size_t)rr*512 + kn + kk] : 0.f;
            }
            #pragma unroll
            for (int i = 0; i < 8; i++) {
                int l = tid + i*256;
                int kk = l >> 6, f = l & 63;
                int krow = kn + kk;
                rb[i] = (krow < M2D) ? Wmb[(size_t)krow*FD + f] : 0.f;
            }
        }
        #pragma unroll 8
        for (int k = 0; k < 32; k++) {
            float a0 = Ts[tm][k], a1 = Ts[tm+1][k], a2 = Ts[tm+2][k], a3 = Ts[tm+3][k];
            float4 b = *(const float4*)&Ws[k][tf];
            acc[0][0] += a0*b.x; acc[0][1] += a0*b.y; acc[0][2] += a0*b.z; acc[0][3] += a0*b.w;
            acc[1][0] += a1*b.x; acc[1][1] += a1*b.y; acc[1][2] += a1*b.z; acc[1][3] += a1*b.w;
            acc[2][0] += a2*b.x; acc[2][1] += a2*b.y; acc[2][2] += a2*b.z; acc[2][3] += a2*b.w;
            acc[3][0] += a3*b.x; acc[3][1] += a3*b.y; acc[3][2] += a3*b.z; acc[3][3] += a3*b.w;
        }
        __syncthreads();
    }
    #pragma unroll
    for (int i = 0; i < 4; i++) {
        int r = r0 + tm + i;
        if (r >= 506) continue;
        int q = r >> 1, reim = r & 1;
        size_t base = (size_t)(m1*QH + q) * FD;
        #pragma unroll
        for (int j = 0; j < 4; j++)
            G1[(base + tf + j)*2 + reim] = acc[i][j];
    }
}

// Gmat[2t..2t+1][f] from G1: fold 9-point DFT over m1, Hermitian weight, 1/4545
__global__ __launch_bounds__(64) void gmat_kernel(const float* __restrict__ G1,
                                                  const float* __restrict__ wp,
                                                  float* __restrict__ Gmat) {
    int t = blockIdx.x;            // [0, 2304)
    int f = threadIdx.x;
    if (t >= THALF) {
        Gmat[(size_t)(2*t)*FD + f] = 0.f;
        Gmat[(size_t)(2*t+1)*FD + f] = 0.f;
        return;
    }
    int p, q;
    if (t < QH) { p = 0; q = t; }
    else { int u = t - QH; p = 1 + u / M2D; q = u % M2D; }
    float gr = 0.f, gi = 0.f;
    #pragma unroll
    for (int m1 = 0; m1 < M1D; m1++) {
        float ar, ai;
        if (q < QH) { size_t o = ((size_t)(m1*QH + q)*FD + f)*2; ar = G1[o]; ai = G1[o+1]; }
        else        { size_t o = ((size_t)(m1*QH + (M2D - q))*FD + f)*2; ar = G1[o]; ai = -G1[o+1]; }
        int pm = (p * m1) % M1D;
        float cr = wp[2*pm], ci = -wp[2*pm+1];   // cis(+2 pi p m1 / 9)
        gr += ar*cr - ai*ci;
        gi += ar*ci + ai*cr;
    }
    float cfac = (t == 0) ? 1.0f : 2.0f;
    float scale = cfac / 4545.0f;
    Gmat[(size_t)(2*t)*FD + f]   =  gr * scale;
    Gmat[(size_t)(2*t+1)*FD + f] = -gi * scale;
}

// one block (256 thr) per node: softmax Z over all j, sparse clamped gather
__global__ __launch_bounds__(256) void attn_agg_kernel(const float* __restrict__ x,
                                                       const float* __restrict__ adj,
                                                       const float* __restrict__ xl,
                                                       const float* __restrict__ xr,
                                                       const float* __restrict__ sumx,
                                                       float* __restrict__ agg) {
    int node = blockIdx.x;
    int b = node >> 10;
    int tid = threadIdx.x;
    __shared__ float xr_s[CH], Zinv[CH], Ssum[CH];
    __shared__ float red[8][CH];
    __shared__ int act_list[NN];
    __shared__ int act_n;
    __shared__ float qv[8][CH];

    if (tid < CH) xr_s[tid] = xr[(size_t)node*CH + tid];
    if (tid == 0) act_n = 0;
    __syncthreads();

    int c = tid & 31, jl = tid >> 5;
    const float* xlb = xl + ((size_t)b << 10) * CH;
    float zacc = 0.f;
    #pragma unroll 4
    for (int j = jl; j < NN; j += 8) {
        float s = xlb[j*CH + c] + xr_s[c];
        s = s > 0.f ? s : 0.01f * s;
        zacc += __expf(s);
    }
    red[jl][c] = zacc;
    __syncthreads();
    if (tid < CH) {
        float z = 0.f;
        #pragma unroll
        for (int r = 0; r < 8; r++) z += red[r][tid];
        Zinv[tid] = 1.0f / z;
    }
    const float* adjrow = adj + (size_t)node * NN;
    __syncthreads();
    for (int j = tid; j < NN; j += 256) {
        if (adjrow[j] != 0.f) { int p = atomicAdd(&act_n, 1); act_list[p] = j; }
    }
    __syncthreads();
    int nact = act_n;

    float acc0 = 0.f, acc1 = 0.f, sacc = 0.f;
    int f = tid & 63, n0 = tid >> 6;
    int g = f >> 4;
    int c0 = n0*4 + g, c1 = (n0+4)*4 + g;
    const float* xb = x + ((size_t)b << 10) * FD;

    for (int base = 0; base < nact; base += 8) {
        int cnt = min(8, nact - base);
        if (jl < cnt) {
            int j = act_list[base + jl];
            float s = xlb[j*CH + c] + xr_s[c];
            s = s > 0.f ? s : 0.01f * s;
            float p = __expf(s) * Zinv[c];
            float qq = fmaxf(p, 1e-6f) - 1e-6f;
            qv[jl][c] = qq;
            sacc += qq;
        }
        __syncthreads();
        for (int jb = 0; jb < cnt; jb++) {
            int j = act_list[base + jb];
            float xv = xb[j*FD + f];
            acc0 += qv[jb][c0] * xv;
            acc1 += qv[jb][c1] * xv;
        }
        __syncthreads();
    }
    red[jl][c] = sacc;
    __syncthreads();
    if (tid < CH) {
        float s = 0.f;
        #pragma unroll
        for (int r = 0; r < 8; r++) s += red[r][tid];
        Ssum[tid] = s + (float)NN * 1e-6f;
    }
    __syncthreads();
    float sx = sumx[b*FD + f] * 1e-6f;
    agg[(size_t)node*512 + n0*FD + f]       = (acc0 + sx) / Ssum[c0];
    agg[(size_t)node*512 + (n0+4)*FD + f]   = (acc1 + sx) / Ssum[c1];
}

// A2 = aggc @ Wt : [4096 x 64] @ [64 x 512] per chunk. grid (64 mtiles, 8 ntiles)
// Register-batched staging (32 loads issued together instead of serialized).
__global__ __launch_bounds__(256) void a_gemm_kernel(const float* __restrict__ aggc,
                                                     const float* __restrict__ Wt,
                                                     float* __restrict__ A2) {
    int mt = blockIdx.x, nt = blockIdx.y;
    int tid = threadIdx.x;
    __shared__ float As2[64][65];   // As2[k][r]
    __shared__ float Bs[64][64];    // Bs[k][c]
    float acc[4][4] = {{0.f}};
    int tm = (tid >> 4) * 4, tf = (tid & 15) * 4;
    float ra[16], rb[16];
    #pragma unroll
    for (int i = 0; i < 16; i++) {
        int l = tid + i*256;
        int r = l >> 6, k = l & 63;
        ra[i] = aggc[(size_t)(mt*64 + r)*64 + k];
    }
    #pragma unroll
    for (int i = 0; i < 16; i++) {
        int l = tid + i*256;
        int k = l >> 6, cc = l & 63;
        rb[i] = Wt[(size_t)k*512 + nt*64 + cc];
    }
    #pragma unroll
    for (int i = 0; i < 16; i++) {
        int l = tid + i*256;
        As2[l & 63][l >> 6] = ra[i];
    }
    #pragma unroll
    for (int i = 0; i < 16; i++) {
        int l = tid + i*256;
        Bs[l >> 6][l & 63] = rb[i];
    }
    __syncthreads();
    #pragma unroll 8
    for (int k = 0; k < 64; k++) {
        float a0 = As2[k][tm], a1 = As2[k][tm+1], a2 = As2[k][tm+2], a3 = As2[k][tm+3];
        float4 b = *(const float4*)&Bs[k][tf];
        acc[0][0] += a0*b.x; acc[0][1] += a0*b.y; acc[0][2] += a0*b.z; acc[0][3] += a0*b.w;
        acc[1][0] += a1*b.x; acc[1][1] += a1*b.y; acc[1][2] += a1*b.z; acc[1][3] += a1*b.w;
        acc[2][0] += a2*b.x; acc[2][1] += a2*b.y; acc[2][2] += a2*b.z; acc[2][3] += a2*b.w;
        acc[3][0] += a3*b.x; acc[3][1] += a3*b.y; acc[3][2] += a3*b.z; acc[3][3] += a3*b.w;
    }
    #pragma unroll
    for (int i = 0; i < 4; i++) {
        float4 v = make_float4(acc[i][0], acc[i][1], acc[i][2], acc[i][3]);
        *(float4*)&A2[(size_t)(mt*64 + tm + i)*512 + nt*64 + tf] = v;
    }
}

// one block (256 thr) per node: Y half-grid from A2 via complex products
__global__ __launch_bounds__(256) void y_kernel(const float* __restrict__ A2,
                                                const float* __restrict__ wp_g,
                                                float* __restrict__ Y, int node0) {
    int nl = blockIdx.x;
    int node = node0 + nl;
    int tid = threadIdx.x;
    __shared__ float2 AL[8][256];
    __shared__ float wpL[M1D*2];

    const float2* A2c = (const float2*)(A2 + (size_t)(nl*8)*512);
    float2 rl[8];
    #pragma unroll
    for (int i = 0; i < 8; i++) {
        int idx = tid + i*256;
        rl[i] = (idx < 8*QH) ? A2c[(idx/QH)*256 + (idx%QH)] : make_float2(0.f, 0.f);
    }
    #pragma unroll
    for (int i = 0; i < 8; i++) {
        int idx = tid + i*256;
        if (idx < 8*QH) AL[idx/QH][idx%QH] = rl[i];
    }
    if (tid < M1D*2) wpL[tid] = wp_g[tid];
    __syncthreads();

    float* Yrow = Y + (size_t)node * KPAD;
    for (int t = tid; t < KPAD/2; t += 256) {
        if (t >= THALF) { Yrow[2*t] = 0.f; Yrow[2*t+1] = 0.f; continue; }
        int p, q;
        if (t < QH) { p = 0; q = t; }
        else { int u = t - QH; p = 1 + u / M2D; q = u % M2D; }
        float cp = wpL[2*p], sp = wpL[2*p+1];      // e^{-2 pi i p / 9}
        int qq; float csign;
        if (q < QH) { qq = q; csign = 1.f; } else { qq = M2D - q; csign = -1.f; }
        float Pr = 1.f, Pi = 0.f, rp = 1.f;
        #pragma unroll
        for (int n = 0; n < 8; n++) {
            float2 Av = AL[n][qq];
            float Ar = Av.x, Ai = csign * Av.y;
            float Xr = cp - Ar, Xi = sp - Ai;
            float m2 = Xr*Xr + Xi*Xi;
            rp *= (sqrtf(m2) + 1e-6f);
            float nPr = Pr*Xr - Pi*Xi;
            Pi = Pr*Xi + Pi*Xr; Pr = nPr;
        }
        float pAbs = sqrtf(Pr*Pr + Pi*Pi);
        float rp8 = sqrtf(sqrtf(sqrtf(rp)));
        float s = rp8 / fmaxf(pAbs, 1e-20f);
        Yrow[2*t]   = s * Pr;
        Yrow[2*t+1] = s * Pi;
    }
}

// partials[kc] = Y[:, kc-chunk] @ Gmat[kc-chunk, :] ; grid (32 Mtiles, 8 kc)
// Register-batched + double-buffered staging.
__global__ __launch_bounds__(256) void gemm_kernel(const float* __restrict__ Y,
                                                   const float* __restrict__ Gmat,
                                                   float* __restrict__ part) {
    int mtile = blockIdx.x, kc = blockIdx.y;
    int tid = threadIdx.x;
    __shared__ float Yt2[32][65];   // Yt2[k][r]
    __shared__ float Gt[32][64];
    int m0 = mtile * 64;
    int k0 = kc * KCHUNK;
    float acc[4][4] = {{0.f}};
    int tm = (tid >> 4) * 4;
    int tf = (tid & 15) * 4;
    float ra[8], rb[8];
    #pragma unroll
    for (int i = 0; i < 8; i++) {
        int l = tid + i*256;
        int r = l >> 5, kk = l & 31;
        ra[i] = Y[(size_t)(m0 + r)*KPAD + k0 + kk];
    }
    #pragma unroll
    for (int i = 0; i < 8; i++) {
        int l = tid + i*256;
        int kk = l >> 6, cc = l & 63;
        rb[i] = Gmat[(size_t)(k0 + kk)*FD + cc];
    }
    for (int ks = 0; ks < KCHUNK; ks += 32) {
        #pragma unroll
        for (int i = 0; i < 8; i++) {
            int l = tid + i*256;
            Yt2[l & 31][l >> 5] = ra[i];
        }
        #pragma unroll
        for (int i = 0; i < 8; i++) {
            int l = tid + i*256;
            Gt[l >> 6][l & 63] = rb[i];
        }
        __syncthreads();
        if (ks + 32 < KCHUNK) {
            int kn = k0 + ks + 32;
            #pragma unroll
            for (int i = 0; i < 8; i++) {
                int l = tid + i*256;
                int r = l >> 5, kk = l & 31;
                ra[i] = Y[(size_t)(m0 + r)*KPAD + kn + kk];
            }
            #pragma unroll
            for (int i = 0; i < 8; i++) {
                int l = tid + i*256;
                int kk = l >> 6, cc = l & 63;
                rb[i] = Gmat[(size_t)(kn + kk)*FD + cc];
            }
        }
        #pragma unroll 8
        for (int k = 0; k < 32; k++) {
            float a0 = Yt2[k][tm], a1 = Yt2[k][tm+1], a2 = Yt2[k][tm+2], a3 = Yt2[k][tm+3];
            float4 b = *(const float4*)&Gt[k][tf];
            acc[0][0] += a0*b.x; acc[0][1] += a0*b.y; acc[0][2] += a0*b.z; acc[0][3] += a0*b.w;
            acc[1][0] += a1*b.x; acc[1][1] += a1*b.y; acc[1][2] += a1*b.z; acc[1][3] += a1*b.w;
            acc[2][0] += a2*b.x; acc[2][1] += a2*b.y; acc[2][2] += a2*b.z; acc[2][3] += a2*b.w;
            acc[3][0] += a3*b.x; acc[3][1] += a3*b.y; acc[3][2] += a3*b.z; acc[3][3] += a3*b.w;
        }
        __syncthreads();
    }
    float* prow = part + (size_t)kc * (2048*FD);
    #pragma unroll
    for (int i = 0; i < 4; i++) {
        float4 v = make_float4(acc[i][0], acc[i][1], acc[i][2], acc[i][3]);
        *(float4*)&prow[(size_t)(m0 + tm + i)*FD + tf] = v;
    }
}

// sum 8 partials + bias + mask -> out
__global__ __launch_bounds__(256) void reduce_kernel(const float* __restrict__ part,
                                                     const float* __restrict__ bm,
                                                     const float* __restrict__ mask,
                                                     float* __restrict__ out) {
    int idx = blockIdx.x * 256 + threadIdx.x;   // float4 index over 2048*64/4 = 32768
    if (idx >= 32768) return;
    const float4* p4 = (const float4*)part;
    float4 s = p4[idx];
    #pragma unroll
    for (int kc = 1; kc < KSPLIT; kc++) {
        float4 v = p4[(size_t)kc*32768 + idx];
        s.x += v.x; s.y += v.y; s.z += v.z; s.w += v.w;
    }
    int f0 = (idx & 15) * 4;
    int node = idx >> 4;
    float mk = mask[node];
    s.x = (s.x + bm[f0])   * mk;
    s.y = (s.y + bm[f0+1]) * mk;
    s.z = (s.z + bm[f0+2]) * mk;
    s.w = (s.w + bm[f0+3]) * mk;
    ((float4*)out)[idx] = s;
}

extern "C" void kernel_launch(void* const* d_in, const int* in_sizes, int n_in,
                              void* d_out, int out_size, void* d_ws, size_t ws_size,
                              hipStream_t stream) {
    const float* x    = (const float*)d_in[0];
    const float* adj  = (const float*)d_in[1];
    const float* mask = (const float*)d_in[2];
    const float* Wl   = (const float*)d_in[3];
    const float* bl   = (const float*)d_in[4];
    const float* Wr   = (const float*)d_in[5];
    const float* br   = (const float*)d_in[6];
    const float* Wm   = (const float*)d_in[9];
    const float* bm   = (const float*)d_in[10];
    float* out = (float*)d_out;
    float* ws  = (float*)d_ws;

    float* tw   = ws + OFF_TW;
    float* wp   = ws + OFF_WP;
    float* sumx = ws + OFF_SUMX;
    float* G1   = ws + OFF_G1;
    float* Gmat = ws + OFF_GMAT;
    float* xl   = ws + OFF_XL;
    float* xr   = ws + OFF_XR;
    float* agg  = ws + OFF_AGG;
    float* part = ws + OFF_AGG;   // alias: agg dead before gemm_kernel
    float* T    = ws + OFF_Y;     // alias: T dead before y_kernel writes Y
    float* Y    = ws + OFF_Y;
    float* A2   = ws + OFF_A2;
    float* Wt   = ws + OFF_WT;

    hipLaunchKernelGGL(prep_kernel, dim3(1), dim3(512), 0, stream, tw, wp, sumx);
    hipLaunchKernelGGL(buildT_kernel, dim3((506*512+255)/256), dim3(256), 0, stream, tw, T);
    hipLaunchKernelGGL(buildWt_kernel, dim3(128), dim3(256), 0, stream, tw, Wt);
    hipLaunchKernelGGL(sumx_kernel, dim3(32), dim3(64), 0, stream, x, sumx);
    hipLaunchKernelGGL(proj_kernel, dim3(2048), dim3(64), 0, stream, x, Wl, bl, Wr, br, xl, xr);
    hipLaunchKernelGGL(g1_gemm_kernel, dim3(8, 9), dim3(256), 0, stream, T, Wm, G1);
    hipLaunchKernelGGL(gmat_kernel, dim3(KPAD/2), dim3(64), 0, stream, G1, wp, Gmat);
    hipLaunchKernelGGL(attn_agg_kernel, dim3(2048), dim3(256), 0, stream, x, adj, xl, xr, sumx, agg);
    for (int c = 0; c < 4; c++) {
        const float* aggc = agg + (size_t)c * NCHUNK * 512;
        hipLaunchKernelGGL(a_gemm_kernel, dim3(64, 8), dim3(256), 0, stream, aggc, Wt, A2);
        hipLaunchKernelGGL(y_kernel, dim3(NCHUNK), dim3(256), 0, stream, A2, wp, Y, c * NCHUNK);
    }
    hipLaunchKernelGGL(gemm_kernel, dim3(32, KSPLIT), dim3(256), 0, stream, Y, Gmat, part);
    hipLaunchKernelGGL(reduce_kernel, dim3(128), dim3(256), 0, stream, part, bm, mask, out);
}

// Round 5
// 257.513 us; speedup vs baseline: 1.7070x; 1.1965x over previous
//
#include <hip/hip_runtime.h>
#include <math.h>

#define NN 1024
#define FD 64
#define CH 32          // K*H
#define M1D 9
#define M2D 505
#define QH 253         // q in [0,252] stored
#define THALF 2273     // half-grid points
#define KPAD 4608
#define KSPLIT 16
#define KCHUNK 288     // 4608/16 = 9*32

// ws layout (floats); ws_size = 256 MiB (observed via harness poison fill)
#define OFF_TW    0                       // 1010 (pad 1024)
#define OFF_WP    1024                    // 18 (pad 32)
#define OFF_SUMX  1056                    // 128 (pad to 1184)
#define OFF_G1    1184                    // 9*253*64*2 = 291456
#define OFF_GMAT  292640                  // 4608*64 = 294912
#define OFF_XL    587552                  // 65536
#define OFF_XR    653088                  // 65536
#define OFF_AGG   718624                  // 2048*512 = 1048576
#define OFF_PART  1767200                 // 16*131072 = 2097152
#define OFF_Y     3864352                 // 2048*4608 = 9437184 ; first 259072 ALIASED as T early
#define OFF_A2    13301536                // 16384*512 = 8388608
#define OFF_WT    21690144                // 64*512 = 32768
// total = 21,722,912 floats = 86.9 MB

__global__ __launch_bounds__(512) void prep_kernel(float* __restrict__ tw,
                                                   float* __restrict__ wp,
                                                   float* __restrict__ sumx) {
    int t = threadIdx.x;
    if (t < M2D) {
        double a = -2.0 * M_PI * (double)t / (double)M2D;
        tw[2*t] = (float)cos(a); tw[2*t+1] = (float)sin(a);
    }
    if (t < M1D) {
        double a = -2.0 * M_PI * (double)t / (double)M1D;
        wp[2*t] = (float)cos(a); wp[2*t+1] = (float)sin(a);
    }
    if (t < 128) sumx[t] = 0.f;
}

// builds both T and Wt (merged to save a launch)
// T[r][m2] (row stride 512): r=2q+reim. T[2q][m2]=cos(-2pi q m2/505), T[2q+1][m2]=-sin(-..)
// Wt[m][col] (row stride 512): col=2q+reim. Wt[m][2q]=cos(-2pi q m/505), [2q+1]=sin(-..)
__global__ __launch_bounds__(256) void build_tw_kernel(const float* __restrict__ tw,
                                                       float* __restrict__ T,
                                                       float* __restrict__ Wt) {
    int idx = blockIdx.x * 256 + threadIdx.x;
    if (idx < 506 * 512) {
        int r = idx >> 9, m2 = idx & 511;
        float v = 0.f;
        if (m2 < M2D) {
            int q = r >> 1;
            int t = (q * m2) % M2D;
            v = (r & 1) ? -tw[2*t+1] : tw[2*t];
        }
        T[idx] = v;
    } else if (idx < 506 * 512 + 64 * 512) {
        int i2 = idx - 506 * 512;
        int m = i2 >> 9, col = i2 & 511;
        float v = 0.f;
        if (col < 506) {
            int q = col >> 1;
            int t = (q * m) % M2D;
            v = (col & 1) ? tw[2*t+1] : tw[2*t];
        }
        Wt[i2] = v;
    }
}

// 32 blocks x 64 threads: partial column sums of x
__global__ __launch_bounds__(64) void sumx_kernel(const float* __restrict__ x,
                                                  float* __restrict__ sumx) {
    int b = blockIdx.x >> 4, chunk = blockIdx.x & 15;
    int f = threadIdx.x;
    const float* xb = x + (size_t)b * NN * FD;
    float acc = 0.f;
    int j0 = chunk * 64;
    #pragma unroll 4
    for (int j = j0; j < j0 + 64; j++) acc += xb[j*FD + f];
    atomicAdd(&sumx[b*FD + f], acc);
}

// 2048 blocks x 64 threads: xl = x@Wl+bl, xr = x@Wr+br
__global__ __launch_bounds__(64) void proj_kernel(const float* __restrict__ x,
                                                  const float* __restrict__ Wl, const float* __restrict__ bl,
                                                  const float* __restrict__ Wr, const float* __restrict__ br,
                                                  float* __restrict__ xl, float* __restrict__ xr) {
    int node = blockIdx.x, tid = threadIdx.x;
    __shared__ float xrow[FD];
    xrow[tid] = x[(size_t)node*FD + tid];
    __syncthreads();
    int c = tid & 31;
    const float* W = (tid < 32) ? Wl : Wr;
    float acc = (tid < 32) ? bl[c] : br[c];
    #pragma unroll
    for (int f = 0; f < FD; f++) acc += xrow[f] * W[f*CH + c];
    float* dst = (tid < 32) ? xl : xr;
    dst[(size_t)node*CH + c] = acc;
}

// G1 rows = T @ Wm[m1] : per m1, [506 x 505(pad512)] @ [505 x 64]
// Register-batched + double-buffered staging.
__global__ __launch_bounds__(256) void g1_gemm_kernel(const float* __restrict__ T,
                                                      const float* __restrict__ Wm,
                                                      float* __restrict__ G1) {
    int mt = blockIdx.x, m1 = blockIdx.y;
    int tid = threadIdx.x;
    __shared__ float Ts[64][33];
    __shared__ float Ws[32][64];
    const float* Wmb = Wm + (size_t)m1 * M2D * FD;
    float acc[4][4] = {{0.f}};
    int tm = (tid >> 4) * 4, tf = (tid & 15) * 4;
    int r0 = mt * 64;
    float ra[8], rb[8];
    #pragma unroll
    for (int i = 0; i < 8; i++) {
        int l = tid + i*256;
        int r = l >> 5, kk = l & 31;
        int rr = r0 + r;
        ra[i] = (rr < 506) ? T[(size_t)rr*512 + kk] : 0.f;
    }
    #pragma unroll
    for (int i = 0; i < 8; i++) {
        int l = tid + i*256;
        int kk = l >> 6, f = l & 63;
        rb[i] = (kk < M2D) ? Wmb[(size_t)kk*FD + f] : 0.f;
    }
    for (int k0 = 0; k0 < 512; k0 += 32) {
        #pragma unroll
        for (int i = 0; i < 8; i++) {
            int l = tid + i*256;
            Ts[l >> 5][l & 31] = ra[i];
        }
        #pragma unroll
        for (int i = 0; i < 8; i++) {
            int l = tid + i*256;
            Ws[l >> 6][l & 63] = rb[i];
        }
        __syncthreads();
        if (k0 + 32 < 512) {
            int kn = k0 + 32;
            #pragma unroll
            for (int i = 0; i < 8; i++) {
                int l = tid + i*256;
                int r = l >> 5, kk = l & 31;
                int rr = r0 + r;
                ra[i] = (rr < 506) ? T[(size_t)rr*512 + kn + kk] : 0.f;
            }
            #pragma unroll
            for (int i = 0; i < 8; i++) {
                int l = tid + i*256;
                int kk = l >> 6, f = l & 63;
                int krow = kn + kk;
                rb[i] = (krow < M2D) ? Wmb[(size_t)krow*FD + f] : 0.f;
            }
        }
        #pragma unroll 8
        for (int k = 0; k < 32; k++) {
            float a0 = Ts[tm][k], a1 = Ts[tm+1][k], a2 = Ts[tm+2][k], a3 = Ts[tm+3][k];
            float4 b = *(const float4*)&Ws[k][tf];
            acc[0][0] += a0*b.x; acc[0][1] += a0*b.y; acc[0][2] += a0*b.z; acc[0][3] += a0*b.w;
            acc[1][0] += a1*b.x; acc[1][1] += a1*b.y; acc[1][2] += a1*b.z; acc[1][3] += a1*b.w;
            acc[2][0] += a2*b.x; acc[2][1] += a2*b.y; acc[2][2] += a2*b.z; acc[2][3] += a2*b.w;
            acc[3][0] += a3*b.x; acc[3][1] += a3*b.y; acc[3][2] += a3*b.z; acc[3][3] += a3*b.w;
        }
        __syncthreads();
    }
    #pragma unroll
    for (int i = 0; i < 4; i++) {
        int r = r0 + tm + i;
        if (r >= 506) continue;
        int q = r >> 1, reim = r & 1;
        size_t base = (size_t)(m1*QH + q) * FD;
        #pragma unroll
        for (int j = 0; j < 4; j++)
            G1[(base + tf + j)*2 + reim] = acc[i][j];
    }
}

// Gmat[2t..2t+1][f] from G1: fold 9-point DFT over m1, Hermitian weight, 1/4545
__global__ __launch_bounds__(64) void gmat_kernel(const float* __restrict__ G1,
                                                  const float* __restrict__ wp,
                                                  float* __restrict__ Gmat) {
    int t = blockIdx.x;            // [0, 2304)
    int f = threadIdx.x;
    if (t >= THALF) {
        Gmat[(size_t)(2*t)*FD + f] = 0.f;
        Gmat[(size_t)(2*t+1)*FD + f] = 0.f;
        return;
    }
    int p, q;
    if (t < QH) { p = 0; q = t; }
    else { int u = t - QH; p = 1 + u / M2D; q = u % M2D; }
    float gr = 0.f, gi = 0.f;
    #pragma unroll
    for (int m1 = 0; m1 < M1D; m1++) {
        float ar, ai;
        if (q < QH) { size_t o = ((size_t)(m1*QH + q)*FD + f)*2; ar = G1[o]; ai = G1[o+1]; }
        else        { size_t o = ((size_t)(m1*QH + (M2D - q))*FD + f)*2; ar = G1[o]; ai = -G1[o+1]; }
        int pm = (p * m1) % M1D;
        float cr = wp[2*pm], ci = -wp[2*pm+1];   // cis(+2 pi p m1 / 9)
        gr += ar*cr - ai*ci;
        gi += ar*ci + ai*cr;
    }
    float cfac = (t == 0) ? 1.0f : 2.0f;
    float scale = cfac / 4545.0f;
    Gmat[(size_t)(2*t)*FD + f]   =  gr * scale;
    Gmat[(size_t)(2*t+1)*FD + f] = -gi * scale;
}

// one block (256 thr) per node: softmax Z over all j, sparse clamped gather
__global__ __launch_bounds__(256) void attn_agg_kernel(const float* __restrict__ x,
                                                       const float* __restrict__ adj,
                                                       const float* __restrict__ xl,
                                                       const float* __restrict__ xr,
                                                       const float* __restrict__ sumx,
                                                       float* __restrict__ agg) {
    int node = blockIdx.x;
    int b = node >> 10;
    int tid = threadIdx.x;
    __shared__ float xr_s[CH], Zinv[CH], Ssum[CH];
    __shared__ float red[8][CH];
    __shared__ int act_list[NN];
    __shared__ int act_n;
    __shared__ float qv[8][CH];

    if (tid < CH) xr_s[tid] = xr[(size_t)node*CH + tid];
    if (tid == 0) act_n = 0;
    __syncthreads();

    int c = tid & 31, jl = tid >> 5;
    const float* xlb = xl + ((size_t)b << 10) * CH;
    float zacc = 0.f;
    #pragma unroll 4
    for (int j = jl; j < NN; j += 8) {
        float s = xlb[j*CH + c] + xr_s[c];
        s = s > 0.f ? s : 0.01f * s;
        zacc += __expf(s);
    }
    red[jl][c] = zacc;
    __syncthreads();
    if (tid < CH) {
        float z = 0.f;
        #pragma unroll
        for (int r = 0; r < 8; r++) z += red[r][tid];
        Zinv[tid] = 1.0f / z;
    }
    const float* adjrow = adj + (size_t)node * NN;
    __syncthreads();
    for (int j = tid; j < NN; j += 256) {
        if (adjrow[j] != 0.f) { int p = atomicAdd(&act_n, 1); act_list[p] = j; }
    }
    __syncthreads();
    int nact = act_n;

    float acc0 = 0.f, acc1 = 0.f, sacc = 0.f;
    int f = tid & 63, n0 = tid >> 6;
    int g = f >> 4;
    int c0 = n0*4 + g, c1 = (n0+4)*4 + g;
    const float* xb = x + ((size_t)b << 10) * FD;

    for (int base = 0; base < nact; base += 8) {
        int cnt = min(8, nact - base);
        if (jl < cnt) {
            int j = act_list[base + jl];
            float s = xlb[j*CH + c] + xr_s[c];
            s = s > 0.f ? s : 0.01f * s;
            float p = __expf(s) * Zinv[c];
            float qq = fmaxf(p, 1e-6f) - 1e-6f;
            qv[jl][c] = qq;
            sacc += qq;
        }
        __syncthreads();
        for (int jb = 0; jb < cnt; jb++) {
            int j = act_list[base + jb];
            float xv = xb[j*FD + f];
            acc0 += qv[jb][c0] * xv;
            acc1 += qv[jb][c1] * xv;
        }
        __syncthreads();
    }
    red[jl][c] = sacc;
    __syncthreads();
    if (tid < CH) {
        float s = 0.f;
        #pragma unroll
        for (int r = 0; r < 8; r++) s += red[r][tid];
        Ssum[tid] = s + (float)NN * 1e-6f;
    }
    __syncthreads();
    float sx = sumx[b*FD + f] * 1e-6f;
    agg[(size_t)node*512 + n0*FD + f]       = (acc0 + sx) / Ssum[c0];
    agg[(size_t)node*512 + (n0+4)*FD + f]   = (acc1 + sx) / Ssum[c1];
}

// A2 = agg @ Wt : [16384 x 64] @ [64 x 512]. grid (256 mtiles, 8 ntiles)
// Register-batched staging; A-tile padded to 68 for aligned ds_read_b128.
__global__ __launch_bounds__(256) void a_gemm_kernel(const float* __restrict__ agg,
                                                     const float* __restrict__ Wt,
                                                     float* __restrict__ A2) {
    int mt = blockIdx.x, nt = blockIdx.y;
    int tid = threadIdx.x;
    __shared__ float As2[64][68];   // As2[k][r], pad 68 -> [k][tm] float4-aligned
    __shared__ float Bs[64][64];    // Bs[k][c]
    float acc[4][4] = {{0.f}};
    int tm = (tid >> 4) * 4, tf = (tid & 15) * 4;
    float ra[16], rb[16];
    #pragma unroll
    for (int i = 0; i < 16; i++) {
        int l = tid + i*256;
        int r = l >> 6, k = l & 63;
        ra[i] = agg[(size_t)(mt*64 + r)*64 + k];
    }
    #pragma unroll
    for (int i = 0; i < 16; i++) {
        int l = tid + i*256;
        int k = l >> 6, cc = l & 63;
        rb[i] = Wt[(size_t)k*512 + nt*64 + cc];
    }
    #pragma unroll
    for (int i = 0; i < 16; i++) {
        int l = tid + i*256;
        As2[l & 63][l >> 6] = ra[i];
    }
    #pragma unroll
    for (int i = 0; i < 16; i++) {
        int l = tid + i*256;
        Bs[l >> 6][l & 63] = rb[i];
    }
    __syncthreads();
    #pragma unroll 8
    for (int k = 0; k < 64; k++) {
        float4 a = *(const float4*)&As2[k][tm];
        float4 b = *(const float4*)&Bs[k][tf];
        acc[0][0] += a.x*b.x; acc[0][1] += a.x*b.y; acc[0][2] += a.x*b.z; acc[0][3] += a.x*b.w;
        acc[1][0] += a.y*b.x; acc[1][1] += a.y*b.y; acc[1][2] += a.y*b.z; acc[1][3] += a.y*b.w;
        acc[2][0] += a.z*b.x; acc[2][1] += a.z*b.y; acc[2][2] += a.z*b.z; acc[2][3] += a.z*b.w;
        acc[3][0] += a.w*b.x; acc[3][1] += a.w*b.y; acc[3][2] += a.w*b.z; acc[3][3] += a.w*b.w;
    }
    #pragma unroll
    for (int i = 0; i < 4; i++) {
        float4 v = make_float4(acc[i][0], acc[i][1], acc[i][2], acc[i][3]);
        *(float4*)&A2[(size_t)(mt*64 + tm + i)*512 + nt*64 + tf] = v;
    }
}

// one block (256 thr) per node: Y half-grid from A2 via complex products
__global__ __launch_bounds__(256) void y_kernel(const float* __restrict__ A2,
                                                const float* __restrict__ wp_g,
                                                float* __restrict__ Y) {
    int node = blockIdx.x;
    int tid = threadIdx.x;
    __shared__ float2 AL[8][256];
    __shared__ float wpL[M1D*2];

    const float2* A2c = (const float2*)(A2 + (size_t)(node*8)*512);
    float2 rl[8];
    #pragma unroll
    for (int i = 0; i < 8; i++) {
        int idx = tid + i*256;
        rl[i] = (idx < 8*QH) ? A2c[(idx/QH)*256 + (idx%QH)] : make_float2(0.f, 0.f);
    }
    #pragma unroll
    for (int i = 0; i < 8; i++) {
        int idx = tid + i*256;
        if (idx < 8*QH) AL[idx/QH][idx%QH] = rl[i];
    }
    if (tid < M1D*2) wpL[tid] = wp_g[tid];
    __syncthreads();

    float* Yrow = Y + (size_t)node * KPAD;
    for (int t = tid; t < KPAD/2; t += 256) {
        if (t >= THALF) { Yrow[2*t] = 0.f; Yrow[2*t+1] = 0.f; continue; }
        int p, q;
        if (t < QH) { p = 0; q = t; }
        else { int u = t - QH; p = 1 + u / M2D; q = u % M2D; }
        float cp = wpL[2*p], sp = wpL[2*p+1];      // e^{-2 pi i p / 9}
        int qq; float csign;
        if (q < QH) { qq = q; csign = 1.f; } else { qq = M2D - q; csign = -1.f; }
        float Pr = 1.f, Pi = 0.f, rp = 1.f;
        #pragma unroll
        for (int n = 0; n < 8; n++) {
            float2 Av = AL[n][qq];
            float Ar = Av.x, Ai = csign * Av.y;
            float Xr = cp - Ar, Xi = sp - Ai;
            float m2 = Xr*Xr + Xi*Xi;
            rp *= (sqrtf(m2) + 1e-6f);
            float nPr = Pr*Xr - Pi*Xi;
            Pi = Pr*Xi + Pi*Xr; Pr = nPr;
        }
        float pAbs = sqrtf(Pr*Pr + Pi*Pi);
        float rp8 = sqrtf(sqrtf(sqrtf(rp)));
        float s = rp8 / fmaxf(pAbs, 1e-20f);
        Yrow[2*t]   = s * Pr;
        Yrow[2*t+1] = s * Pi;
    }
}

// partials[kc] = Y[:, kc-chunk] @ Gmat[kc-chunk, :] ; grid (32 Mtiles, 16 kc)
// Register-batched + double-buffered staging; A-tile padded 68 for float4 reads.
__global__ __launch_bounds__(256) void gemm_kernel(const float* __restrict__ Y,
                                                   const float* __restrict__ Gmat,
                                                   float* __restrict__ part) {
    int mtile = blockIdx.x, kc = blockIdx.y;
    int tid = threadIdx.x;
    __shared__ float Yt2[32][68];   // Yt2[k][r], pad 68 -> [k][tm] float4-aligned
    __shared__ float Gt[32][64];
    int m0 = mtile * 64;
    int k0 = kc * KCHUNK;
    float acc[4][4] = {{0.f}};
    int tm = (tid >> 4) * 4;
    int tf = (tid & 15) * 4;
    float ra[8], rb[8];
    #pragma unroll
    for (int i = 0; i < 8; i++) {
        int l = tid + i*256;
        int r = l >> 5, kk = l & 31;
        ra[i] = Y[(size_t)(m0 + r)*KPAD + k0 + kk];
    }
    #pragma unroll
    for (int i = 0; i < 8; i++) {
        int l = tid + i*256;
        int kk = l >> 6, cc = l & 63;
        rb[i] = Gmat[(size_t)(k0 + kk)*FD + cc];
    }
    for (int ks = 0; ks < KCHUNK; ks += 32) {
        #pragma unroll
        for (int i = 0; i < 8; i++) {
            int l = tid + i*256;
            Yt2[l & 31][l >> 5] = ra[i];
        }
        #pragma unroll
        for (int i = 0; i < 8; i++) {
            int l = tid + i*256;
            Gt[l >> 6][l & 63] = rb[i];
        }
        __syncthreads();
        if (ks + 32 < KCHUNK) {
            int kn = k0 + ks + 32;
            #pragma unroll
            for (int i = 0; i < 8; i++) {
                int l = tid + i*256;
                int r = l >> 5, kk = l & 31;
                ra[i] = Y[(size_t)(m0 + r)*KPAD + kn + kk];
            }
            #pragma unroll
            for (int i = 0; i < 8; i++) {
                int l = tid + i*256;
                int kk = l >> 6, cc = l & 63;
                rb[i] = Gmat[(size_t)(kn + kk)*FD + cc];
            }
        }
        #pragma unroll 8
        for (int k = 0; k < 32; k++) {
            float4 a = *(const float4*)&Yt2[k][tm];
            float4 b = *(const float4*)&Gt[k][tf];
            acc[0][0] += a.x*b.x; acc[0][1] += a.x*b.y; acc[0][2] += a.x*b.z; acc[0][3] += a.x*b.w;
            acc[1][0] += a.y*b.x; acc[1][1] += a.y*b.y; acc[1][2] += a.y*b.z; acc[1][3] += a.y*b.w;
            acc[2][0] += a.z*b.x; acc[2][1] += a.z*b.y; acc[2][2] += a.z*b.z; acc[2][3] += a.z*b.w;
            acc[3][0] += a.w*b.x; acc[3][1] += a.w*b.y; acc[3][2] += a.w*b.z; acc[3][3] += a.w*b.w;
        }
        __syncthreads();
    }
    float* prow = part + (size_t)kc * (2048*FD);
    #pragma unroll
    for (int i = 0; i < 4; i++) {
        float4 v = make_float4(acc[i][0], acc[i][1], acc[i][2], acc[i][3]);
        *(float4*)&prow[(size_t)(m0 + tm + i)*FD + tf] = v;
    }
}

// sum 16 partials + bias + mask -> out
__global__ __launch_bounds__(256) void reduce_kernel(const float* __restrict__ part,
                                                     const float* __restrict__ bm,
                                                     const float* __restrict__ mask,
                                                     float* __restrict__ out) {
    int idx = blockIdx.x * 256 + threadIdx.x;   // float4 index over 2048*64/4 = 32768
    if (idx >= 32768) return;
    const float4* p4 = (const float4*)part;
    float4 s = p4[idx];
    #pragma unroll
    for (int kc = 1; kc < KSPLIT; kc++) {
        float4 v = p4[(size_t)kc*32768 + idx];
        s.x += v.x; s.y += v.y; s.z += v.z; s.w += v.w;
    }
    int f0 = (idx & 15) * 4;
    int node = idx >> 4;
    float mk = mask[node];
    s.x = (s.x + bm[f0])   * mk;
    s.y = (s.y + bm[f0+1]) * mk;
    s.z = (s.z + bm[f0+2]) * mk;
    s.w = (s.w + bm[f0+3]) * mk;
    ((float4*)out)[idx] = s;
}

extern "C" void kernel_launch(void* const* d_in, const int* in_sizes, int n_in,
                              void* d_out, int out_size, void* d_ws, size_t ws_size,
                              hipStream_t stream) {
    const float* x    = (const float*)d_in[0];
    const float* adj  = (const float*)d_in[1];
    const float* mask = (const float*)d_in[2];
    const float* Wl   = (const float*)d_in[3];
    const float* bl   = (const float*)d_in[4];
    const float* Wr   = (const float*)d_in[5];
    const float* br   = (const float*)d_in[6];
    const float* Wm   = (const float*)d_in[9];
    const float* bm   = (const float*)d_in[10];
    float* out = (float*)d_out;
    float* ws  = (float*)d_ws;

    float* tw   = ws + OFF_TW;
    float* wp   = ws + OFF_WP;
    float* sumx = ws + OFF_SUMX;
    float* G1   = ws + OFF_G1;
    float* Gmat = ws + OFF_GMAT;
    float* xl   = ws + OFF_XL;
    float* xr   = ws + OFF_XR;
    float* agg  = ws + OFF_AGG;
    float* part = ws + OFF_PART;
    float* T    = ws + OFF_Y;     // alias: T dead before y_kernel writes Y
    float* Y    = ws + OFF_Y;
    float* A2   = ws + OFF_A2;
    float* Wt   = ws + OFF_WT;

    hipLaunchKernelGGL(prep_kernel, dim3(1), dim3(512), 0, stream, tw, wp, sumx);
    hipLaunchKernelGGL(build_tw_kernel, dim3((506*512 + 64*512 + 255)/256), dim3(256), 0, stream, tw, T, Wt);
    hipLaunchKernelGGL(sumx_kernel, dim3(32), dim3(64), 0, stream, x, sumx);
    hipLaunchKernelGGL(proj_kernel, dim3(2048), dim3(64), 0, stream, x, Wl, bl, Wr, br, xl, xr);
    hipLaunchKernelGGL(g1_gemm_kernel, dim3(8, 9), dim3(256), 0, stream, T, Wm, G1);
    hipLaunchKernelGGL(gmat_kernel, dim3(KPAD/2), dim3(64), 0, stream, G1, wp, Gmat);
    hipLaunchKernelGGL(attn_agg_kernel, dim3(2048), dim3(256), 0, stream, x, adj, xl, xr, sumx, agg);
    hipLaunchKernelGGL(a_gemm_kernel, dim3(256, 8), dim3(256), 0, stream, agg, Wt, A2);
    hipLaunchKernelGGL(y_kernel, dim3(2048), dim3(256), 0, stream, A2, wp, Y);
    hipLaunchKernelGGL(gemm_kernel, dim3(32, KSPLIT), dim3(256), 0, stream, Y, Gmat, part);
    hipLaunchKernelGGL(reduce_kernel, dim3(128), dim3(256), 0, stream, part, bm, mask, out);
}